// Round 1
// baseline (2925.746 us; speedup 1.0000x reference)
//
#include <hip/hip_runtime.h>

#define DIM 64

// Edge-parallel bidirectional scatter: 64 lanes per edge, lane d handles dim d.
// Adds u[src] into acc_i[dst] and i[dst] into acc_u[src]. Optionally counts
// degrees (layer 1 only; counts are graph-invariant across layers).
__global__ void lgcn_scatter(const float* __restrict__ u,
                             const float* __restrict__ i,
                             const int* __restrict__ src,
                             const int* __restrict__ dst,
                             float* __restrict__ acc_u,
                             float* __restrict__ acc_i,
                             float* cnt_u, float* cnt_i,
                             int E) {
    int tid  = blockIdx.x * blockDim.x + threadIdx.x;
    int e    = tid >> 6;          // edge index
    int lane = tid & 63;          // dim index
    if (e >= E) return;
    int s = src[e];
    int t = dst[e];
    float uv = u[(size_t)s * DIM + lane];
    float iv = i[(size_t)t * DIM + lane];
    atomicAdd(&acc_i[(size_t)t * DIM + lane], uv);
    atomicAdd(&acc_u[(size_t)s * DIM + lane], iv);
    if (cnt_u != nullptr && lane == 0) {
        atomicAdd(&cnt_u[s], 1.0f);
        atomicAdd(&cnt_i[t], 1.0f);
    }
}

// In-place segment-mean finalize: acc[k] = cnt>0 ? acc[k]/cnt : 0
__global__ void lgcn_finalize(float* __restrict__ acc,
                              const float* __restrict__ cnt,
                              size_t n) {
    size_t k = (size_t)blockIdx.x * blockDim.x + threadIdx.x;
    if (k >= n) return;
    float c = cnt[k >> 6];
    float v = acc[k];
    acc[k] = (c > 0.0f) ? v / c : 0.0f;
}

// out[k] = (x0[k] + x1[k] + mean(out_acc[k])) / 3, in place over out_acc.
__global__ void lgcn_combine(const float* __restrict__ x0,
                             const float* __restrict__ x1,
                             float* __restrict__ out_acc,
                             const float* __restrict__ cnt,
                             size_t n) {
    size_t k = (size_t)blockIdx.x * blockDim.x + threadIdx.x;
    if (k >= n) return;
    float c = cnt[k >> 6];
    float m = (c > 0.0f) ? out_acc[k] / c : 0.0f;
    out_acc[k] = (x0[k] + x1[k] + m) * (1.0f / 3.0f);
}

extern "C" void kernel_launch(void* const* d_in, const int* in_sizes, int n_in,
                              void* d_out, int out_size, void* d_ws, size_t ws_size,
                              hipStream_t stream) {
    const float* u0  = (const float*)d_in[0];
    const float* i0  = (const float*)d_in[1];
    const int*   src = (const int*)d_in[2];
    const int*   dst = (const int*)d_in[3];

    const size_t n_users = (size_t)in_sizes[0] / DIM;   // 200000
    const size_t n_items = (size_t)in_sizes[1] / DIM;   // 100000
    const int    E       = in_sizes[2];                 // 3000000

    const size_t u_elems = n_users * DIM;               // 12.8M
    const size_t i_elems = n_items * DIM;               // 6.4M

    // Workspace layout (floats): acc_u | acc_i | cnt_u | cnt_i  (~78 MB)
    float* acc_u = (float*)d_ws;
    float* acc_i = acc_u + u_elems;
    float* cnt_u = acc_i + i_elems;
    float* cnt_i = cnt_u + n_users;
    const size_t ws_floats = u_elems + i_elems + n_users + n_items;

    // d_out doubles as the layer-2 accumulator.
    float* out_u = (float*)d_out;
    float* out_i = out_u + u_elems;

    // Zero accumulators (ws and out are poisoned to 0xAA before every launch).
    hipMemsetAsync(d_ws, 0, ws_floats * sizeof(float), stream);
    hipMemsetAsync(d_out, 0, (size_t)out_size * sizeof(float), stream);

    const int BLK = 256;
    const int scatter_blocks = (int)(((size_t)E * 64 + BLK - 1) / BLK);

    // ---- Layer 1: u0,i0 -> acc_u (=sum for u1), acc_i (=sum for i1), counts
    lgcn_scatter<<<scatter_blocks, BLK, 0, stream>>>(
        u0, i0, src, dst, acc_u, acc_i, cnt_u, cnt_i, E);

    lgcn_finalize<<<(int)((u_elems + BLK - 1) / BLK), BLK, 0, stream>>>(acc_u, cnt_u, u_elems);
    lgcn_finalize<<<(int)((i_elems + BLK - 1) / BLK), BLK, 0, stream>>>(acc_i, cnt_i, i_elems);
    // acc_u = u1, acc_i = i1

    // ---- Layer 2: u1,i1 -> out_u (=sum for u2), out_i (=sum for i2)
    lgcn_scatter<<<scatter_blocks, BLK, 0, stream>>>(
        acc_u, acc_i, src, dst, out_u, out_i, nullptr, nullptr, E);

    // ---- Combine: out = (x0 + x1 + x2)/3
    lgcn_combine<<<(int)((u_elems + BLK - 1) / BLK), BLK, 0, stream>>>(u0, acc_u, out_u, cnt_u, u_elems);
    lgcn_combine<<<(int)((i_elems + BLK - 1) / BLK), BLK, 0, stream>>>(i0, acc_i, out_i, cnt_i, i_elems);
}

// Round 2
// 1745.897 us; speedup vs baseline: 1.6758x; 1.6758x over previous
//
#include <hip/hip_runtime.h>

#define DIM 64

// ---------- CSR build ----------

__global__ void edge_hist(const int* __restrict__ src, const int* __restrict__ dst,
                          int* __restrict__ deg_u, int* __restrict__ deg_i, int E) {
    int e = blockIdx.x * blockDim.x + threadIdx.x;
    if (e >= E) return;
    atomicAdd(&deg_u[src[e]], 1);
    atomicAdd(&deg_i[dst[e]], 1);
}

// Single-workgroup exclusive scan (1024 threads, shuffle-based).
// Writes exclusive prefix (segment start offsets) into cur[].
__global__ void exclusive_scan_1b(const int* __restrict__ deg, int* __restrict__ cur, int n) {
    __shared__ int wsums[16];
    __shared__ int s_carry;
    const int lane = threadIdx.x & 63;
    const int wid  = threadIdx.x >> 6;
    if (threadIdx.x == 0) s_carry = 0;
    __syncthreads();
    for (int base = 0; base < n; base += 1024) {
        int i = base + (int)threadIdx.x;
        int v = (i < n) ? deg[i] : 0;
        int incl = v;
        #pragma unroll
        for (int off = 1; off < 64; off <<= 1) {
            int t = __shfl_up(incl, off, 64);
            if (lane >= off) incl += t;
        }
        if (lane == 63) wsums[wid] = incl;
        __syncthreads();
        int woff = 0;
        for (int w = 0; w < wid; ++w) woff += wsums[w];
        if (i < n) cur[i] = s_carry + woff + incl - v;
        __syncthreads();
        if (threadIdx.x == 1023) s_carry += woff + incl;   // chunk total
        __syncthreads();
    }
}

// Places the opposite endpoint into each node's segment. After this kernel,
// cur[k] == inclusive prefix (segment END); start is cur[k-1] (0 for k==0).
__global__ void edge_fill(const int* __restrict__ src, const int* __restrict__ dst,
                          int* cur_u, int* cur_i,
                          int* __restrict__ col_u, int* __restrict__ col_i, int E) {
    int e = blockIdx.x * blockDim.x + threadIdx.x;
    if (e >= E) return;
    int s = src[e], t = dst[e];
    col_u[atomicAdd(&cur_u[s], 1)] = t;   // user s's neighbor item t
    col_i[atomicAdd(&cur_i[t], 1)] = s;   // item t's neighbor user s
}

// ---------- aggregation (one wave per node, lane = dim) ----------

__global__ void gather_mean(const float* __restrict__ feat,
                            const int* __restrict__ ends,
                            const int* __restrict__ col,
                            float* __restrict__ out, int n) {
    int node = blockIdx.x * (blockDim.x >> 6) + (threadIdx.x >> 6);
    int lane = threadIdx.x & 63;
    if (node >= n) return;
    int beg = (node == 0) ? 0 : ends[node - 1];
    int end = ends[node];
    float a0 = 0.f, a1 = 0.f, a2 = 0.f, a3 = 0.f;
    int e = beg;
    for (; e + 3 < end; e += 4) {
        int n0 = col[e], n1 = col[e + 1], n2 = col[e + 2], n3 = col[e + 3];
        a0 += feat[(size_t)n0 * DIM + lane];
        a1 += feat[(size_t)n1 * DIM + lane];
        a2 += feat[(size_t)n2 * DIM + lane];
        a3 += feat[(size_t)n3 * DIM + lane];
    }
    for (; e < end; ++e) a0 += feat[(size_t)col[e] * DIM + lane];
    float sum = (a0 + a1) + (a2 + a3);
    int d = end - beg;
    out[(size_t)node * DIM + lane] = (d > 0) ? sum / (float)d : 0.0f;
}

// out holds x1 on entry; writes (x0 + x1 + mean_nbr(feat)) / 3 in place.
__global__ void gather_mean_combine(const float* __restrict__ feat,
                                    const int* __restrict__ ends,
                                    const int* __restrict__ col,
                                    const float* __restrict__ x0,
                                    float* __restrict__ out, int n) {
    int node = blockIdx.x * (blockDim.x >> 6) + (threadIdx.x >> 6);
    int lane = threadIdx.x & 63;
    if (node >= n) return;
    int beg = (node == 0) ? 0 : ends[node - 1];
    int end = ends[node];
    float a0 = 0.f, a1 = 0.f, a2 = 0.f, a3 = 0.f;
    int e = beg;
    for (; e + 3 < end; e += 4) {
        int n0 = col[e], n1 = col[e + 1], n2 = col[e + 2], n3 = col[e + 3];
        a0 += feat[(size_t)n0 * DIM + lane];
        a1 += feat[(size_t)n1 * DIM + lane];
        a2 += feat[(size_t)n2 * DIM + lane];
        a3 += feat[(size_t)n3 * DIM + lane];
    }
    for (; e < end; ++e) a0 += feat[(size_t)col[e] * DIM + lane];
    float sum = (a0 + a1) + (a2 + a3);
    int d = end - beg;
    float m = (d > 0) ? sum / (float)d : 0.0f;
    size_t k = (size_t)node * DIM + lane;
    out[k] = (x0[k] + out[k] + m) * (1.0f / 3.0f);
}

// out = (x0 + out + x2m) / 3, elementwise.
__global__ void combine3(const float* __restrict__ x0, const float* __restrict__ x2m,
                         float* __restrict__ out, size_t nelem) {
    size_t k = (size_t)blockIdx.x * blockDim.x + threadIdx.x;
    if (k >= nelem) return;
    out[k] = (x0[k] + out[k] + x2m[k]) * (1.0f / 3.0f);
}

extern "C" void kernel_launch(void* const* d_in, const int* in_sizes, int n_in,
                              void* d_out, int out_size, void* d_ws, size_t ws_size,
                              hipStream_t stream) {
    const float* u0  = (const float*)d_in[0];
    const float* i0  = (const float*)d_in[1];
    const int*   src = (const int*)d_in[2];
    const int*   dst = (const int*)d_in[3];

    const int n_users = in_sizes[0] / DIM;   // 200000
    const int n_items = in_sizes[1] / DIM;   // 100000
    const int E       = in_sizes[2];         // 3000000

    const size_t u_elems = (size_t)n_users * DIM;
    const size_t i_elems = (size_t)n_items * DIM;

    // Workspace layout (4-byte units), ~52 MB total:
    //   deg_u | deg_i | cur_u | cur_i | col_u[E] | col_i[E] | tmp_i[i_elems]
    int* deg_u = (int*)d_ws;
    int* deg_i = deg_u + n_users;
    int* cur_u = deg_i + n_items;
    int* cur_i = cur_u + n_users;
    int* col_u = cur_i + n_items;
    int* col_i = col_u + E;
    float* tmp_i = (float*)(col_i + E);

    float* out_u = (float*)d_out;        // holds u1, then final user output
    float* out_i = out_u + u_elems;      // holds i1, then final item output

    const int BLK = 256;
    const int eg = (E + BLK - 1) / BLK;

    // ---- CSR build (graph is identical for both layers) ----
    hipMemsetAsync(deg_u, 0, (size_t)(n_users + n_items) * sizeof(int), stream);
    edge_hist<<<eg, BLK, 0, stream>>>(src, dst, deg_u, deg_i, E);
    exclusive_scan_1b<<<1, 1024, 0, stream>>>(deg_u, cur_u, n_users);
    exclusive_scan_1b<<<1, 1024, 0, stream>>>(deg_i, cur_i, n_items);
    edge_fill<<<eg, BLK, 0, stream>>>(src, dst, cur_u, cur_i, col_u, col_i, E);
    // cur_u/cur_i now hold inclusive segment ends.

    const int ug = (n_users + 3) / 4;    // 4 waves (nodes) per 256-thr block
    const int ig = (n_items + 3) / 4;

    // ---- Layer 1: i1 = mean_nbr(u0), u1 = mean_nbr(i0), written to d_out ----
    gather_mean<<<ig, BLK, 0, stream>>>(u0, cur_i, col_i, out_i, n_items);
    gather_mean<<<ug, BLK, 0, stream>>>(i0, cur_u, col_u, out_u, n_users);

    // ---- Layer 2 item-side mean into ws BEFORE out_u is overwritten ----
    gather_mean<<<ig, BLK, 0, stream>>>(out_u /*u1*/, cur_i, col_i, tmp_i, n_items);

    // ---- Final user: out_u = (u0 + u1 + mean_nbr(i1)) / 3 (out_i intact) ----
    gather_mean_combine<<<ug, BLK, 0, stream>>>(out_i /*i1*/, cur_u, col_u, u0, out_u, n_users);

    // ---- Final item: out_i = (i0 + i1 + tmp_i) / 3 ----
    combine3<<<(int)((i_elems + BLK - 1) / BLK), BLK, 0, stream>>>(i0, tmp_i, out_i, i_elems);
}

// Round 3
// 1128.149 us; speedup vs baseline: 2.5934x; 1.5476x over previous
//
#include <hip/hip_runtime.h>

#define DIM 64
#define NG 8          // node-range groups (≈ XCD count)
#define SCAN_B 1024

// ---------- CSR build ----------

__global__ void edge_hist(const int* __restrict__ src, const int* __restrict__ dst,
                          int* __restrict__ deg_u, int* __restrict__ deg_i, int E) {
    int e = blockIdx.x * blockDim.x + threadIdx.x;
    if (e >= E) return;
    int s = __builtin_nontemporal_load(&src[e]);
    int t = __builtin_nontemporal_load(&dst[e]);
    atomicAdd(&deg_u[s], 1);
    atomicAdd(&deg_i[t], 1);
}

// 3-pass exclusive scan.
// Pass 1: per-block exclusive scan of 1024-elem chunk; block total -> bsum.
__global__ void scan1(const int* __restrict__ deg, int* __restrict__ cur,
                      int* __restrict__ bsum, int n) {
    __shared__ int ws[16];
    int i = blockIdx.x * SCAN_B + threadIdx.x;
    int lane = threadIdx.x & 63, wid = threadIdx.x >> 6;
    int v = (i < n) ? deg[i] : 0;
    int incl = v;
    #pragma unroll
    for (int off = 1; off < 64; off <<= 1) {
        int t = __shfl_up(incl, off, 64);
        if (lane >= off) incl += t;
    }
    if (lane == 63) ws[wid] = incl;
    __syncthreads();
    int woff = 0;
    for (int w = 0; w < wid; ++w) woff += ws[w];
    if (i < n) cur[i] = woff + incl - v;
    if (threadIdx.x == SCAN_B - 1) bsum[blockIdx.x] = woff + incl;
}

// Pass 2: single block, exclusive scan of block sums in place (nb <= 1024).
__global__ void scan2(int* __restrict__ bsum, int nb) {
    __shared__ int ws[16];
    int lane = threadIdx.x & 63, wid = threadIdx.x >> 6;
    int v = ((int)threadIdx.x < nb) ? bsum[threadIdx.x] : 0;
    int incl = v;
    #pragma unroll
    for (int off = 1; off < 64; off <<= 1) {
        int t = __shfl_up(incl, off, 64);
        if (lane >= off) incl += t;
    }
    if (lane == 63) ws[wid] = incl;
    __syncthreads();
    int woff = 0;
    for (int w = 0; w < wid; ++w) woff += ws[w];
    if ((int)threadIdx.x < nb) bsum[threadIdx.x] = woff + incl - v;
}

// Pass 3: add block offsets.
__global__ void scan3(int* __restrict__ cur, const int* __restrict__ bsum, int n) {
    int i = blockIdx.x * SCAN_B + threadIdx.x;
    if (i < n) cur[i] += bsum[blockIdx.x];
}

// Range-partitioned CSR fill. Group g (blockIdx % NG, round-robin across XCDs)
// scans ALL edges but only places endpoints for nodes in its 1/NG range, so
// each 1.5 MB col slice stays resident in one XCD's L2 while its lines fill.
// After this kernel cur_* hold inclusive segment ENDS.
__global__ __launch_bounds__(256) void edge_fill_part(
        const int* __restrict__ src, const int* __restrict__ dst,
        int* __restrict__ cur_u, int* __restrict__ cur_i,
        int* __restrict__ col_u, int* __restrict__ col_i,
        int E, int n_users, int n_items) {
    int g    = blockIdx.x & (NG - 1);
    int bi   = blockIdx.x >> 3;
    int bpg  = gridDim.x >> 3;
    int nthr = bpg * blockDim.x;
    int tid  = bi * blockDim.x + threadIdx.x;

    int uchunk = (n_users + NG - 1) / NG;
    int ulo = g * uchunk, uhi = min(n_users, ulo + uchunk);
    int ichunk = (n_items + NG - 1) / NG;
    int ilo = g * ichunk, ihi = min(n_items, ilo + ichunk);

    for (int e = tid; e < E; e += nthr) {
        int s = __builtin_nontemporal_load(&src[e]);
        if (s >= ulo && s < uhi) {
            int t = __builtin_nontemporal_load(&dst[e]);
            col_u[atomicAdd(&cur_u[s], 1)] = t;
        }
    }
    for (int e = tid; e < E; e += nthr) {
        int t = __builtin_nontemporal_load(&dst[e]);
        if (t >= ilo && t < ihi) {
            int s = __builtin_nontemporal_load(&src[e]);
            col_i[atomicAdd(&cur_i[t], 1)] = s;
        }
    }
}

// ---------- aggregation (one wave per node, lane = dim) ----------

__global__ void gather_mean(const float* __restrict__ feat,
                            const int* __restrict__ ends,
                            const int* __restrict__ col,
                            float* __restrict__ out, int n) {
    int node = blockIdx.x * (blockDim.x >> 6) + (threadIdx.x >> 6);
    int lane = threadIdx.x & 63;
    if (node >= n) return;
    int beg = (node == 0) ? 0 : ends[node - 1];
    int end = ends[node];
    float a0 = 0.f, a1 = 0.f, a2 = 0.f, a3 = 0.f;
    int e = beg;
    for (; e + 3 < end; e += 4) {
        int n0 = col[e], n1 = col[e + 1], n2 = col[e + 2], n3 = col[e + 3];
        a0 += feat[(size_t)n0 * DIM + lane];
        a1 += feat[(size_t)n1 * DIM + lane];
        a2 += feat[(size_t)n2 * DIM + lane];
        a3 += feat[(size_t)n3 * DIM + lane];
    }
    for (; e < end; ++e) a0 += feat[(size_t)col[e] * DIM + lane];
    float sum = (a0 + a1) + (a2 + a3);
    int d = end - beg;
    out[(size_t)node * DIM + lane] = (d > 0) ? sum / (float)d : 0.0f;
}

// out holds x1 on entry; writes (x0 + x1 + mean_nbr(feat)) / 3 in place.
__global__ void gather_mean_combine(const float* __restrict__ feat,
                                    const int* __restrict__ ends,
                                    const int* __restrict__ col,
                                    const float* __restrict__ x0,
                                    float* __restrict__ out, int n) {
    int node = blockIdx.x * (blockDim.x >> 6) + (threadIdx.x >> 6);
    int lane = threadIdx.x & 63;
    if (node >= n) return;
    int beg = (node == 0) ? 0 : ends[node - 1];
    int end = ends[node];
    float a0 = 0.f, a1 = 0.f, a2 = 0.f, a3 = 0.f;
    int e = beg;
    for (; e + 3 < end; e += 4) {
        int n0 = col[e], n1 = col[e + 1], n2 = col[e + 2], n3 = col[e + 3];
        a0 += feat[(size_t)n0 * DIM + lane];
        a1 += feat[(size_t)n1 * DIM + lane];
        a2 += feat[(size_t)n2 * DIM + lane];
        a3 += feat[(size_t)n3 * DIM + lane];
    }
    for (; e < end; ++e) a0 += feat[(size_t)col[e] * DIM + lane];
    float sum = (a0 + a1) + (a2 + a3);
    int d = end - beg;
    float m = (d > 0) ? sum / (float)d : 0.0f;
    size_t k = (size_t)node * DIM + lane;
    out[k] = (x0[k] + out[k] + m) * (1.0f / 3.0f);
}

// out = (x0 + out + x2m) / 3, elementwise.
__global__ void combine3(const float* __restrict__ x0, const float* __restrict__ x2m,
                         float* __restrict__ out, size_t nelem) {
    size_t k = (size_t)blockIdx.x * blockDim.x + threadIdx.x;
    if (k >= nelem) return;
    out[k] = (x0[k] + out[k] + x2m[k]) * (1.0f / 3.0f);
}

extern "C" void kernel_launch(void* const* d_in, const int* in_sizes, int n_in,
                              void* d_out, int out_size, void* d_ws, size_t ws_size,
                              hipStream_t stream) {
    const float* u0  = (const float*)d_in[0];
    const float* i0  = (const float*)d_in[1];
    const int*   src = (const int*)d_in[2];
    const int*   dst = (const int*)d_in[3];

    const int n_users = in_sizes[0] / DIM;   // 200000
    const int n_items = in_sizes[1] / DIM;   // 100000
    const int E       = in_sizes[2];         // 3000000

    const size_t u_elems = (size_t)n_users * DIM;
    const size_t i_elems = (size_t)n_items * DIM;

    // Workspace layout (4-byte units), ~52 MB total:
    // deg_u | deg_i | cur_u | cur_i | col_u[E] | col_i[E] | tmp_i | bsum_u | bsum_i
    int* deg_u = (int*)d_ws;
    int* deg_i = deg_u + n_users;
    int* cur_u = deg_i + n_items;
    int* cur_i = cur_u + n_users;
    int* col_u = cur_i + n_items;
    int* col_i = col_u + E;
    float* tmp_i = (float*)(col_i + E);
    int* bsum_u = (int*)(tmp_i + i_elems);
    int* bsum_i = bsum_u + 1024;

    float* out_u = (float*)d_out;        // holds u1, then final user output
    float* out_i = out_u + u_elems;      // holds i1, then final item output

    const int BLK = 256;
    const int eg = (E + BLK - 1) / BLK;
    const int nb_u = (n_users + SCAN_B - 1) / SCAN_B;   // 196
    const int nb_i = (n_items + SCAN_B - 1) / SCAN_B;   // 98

    // ---- CSR build (graph identical for both layers) ----
    hipMemsetAsync(deg_u, 0, (size_t)(n_users + n_items) * sizeof(int), stream);
    edge_hist<<<eg, BLK, 0, stream>>>(src, dst, deg_u, deg_i, E);

    scan1<<<nb_u, SCAN_B, 0, stream>>>(deg_u, cur_u, bsum_u, n_users);
    scan2<<<1, SCAN_B, 0, stream>>>(bsum_u, nb_u);
    scan3<<<nb_u, SCAN_B, 0, stream>>>(cur_u, bsum_u, n_users);

    scan1<<<nb_i, SCAN_B, 0, stream>>>(deg_i, cur_i, bsum_i, n_items);
    scan2<<<1, SCAN_B, 0, stream>>>(bsum_i, nb_i);
    scan3<<<nb_i, SCAN_B, 0, stream>>>(cur_i, bsum_i, n_items);

    edge_fill_part<<<NG * 160, BLK, 0, stream>>>(src, dst, cur_u, cur_i,
                                                 col_u, col_i, E, n_users, n_items);
    // cur_u/cur_i now hold inclusive segment ends.

    const int ug = (n_users + 3) / 4;    // 4 waves (nodes) per 256-thr block
    const int ig = (n_items + 3) / 4;

    // ---- Layer 1: i1 = mean_nbr(u0), u1 = mean_nbr(i0), written to d_out ----
    gather_mean<<<ig, BLK, 0, stream>>>(u0, cur_i, col_i, out_i, n_items);
    gather_mean<<<ug, BLK, 0, stream>>>(i0, cur_u, col_u, out_u, n_users);

    // ---- Layer 2 item-side mean into ws BEFORE out_u is overwritten ----
    gather_mean<<<ig, BLK, 0, stream>>>(out_u /*u1*/, cur_i, col_i, tmp_i, n_items);

    // ---- Final user: out_u = (u0 + u1 + mean_nbr(i1)) / 3 (out_i intact) ----
    gather_mean_combine<<<ug, BLK, 0, stream>>>(out_i /*i1*/, cur_u, col_u, u0, out_u, n_users);

    // ---- Final item: out_i = (i0 + i1 + tmp_i) / 3 ----
    combine3<<<(int)((i_elems + BLK - 1) / BLK), BLK, 0, stream>>>(i0, tmp_i, out_i, i_elems);
}

// Round 4
// 953.190 us; speedup vs baseline: 3.0694x; 1.1836x over previous
//
#include <hip/hip_runtime.h>

#define DIM 64
#define NG 8
#define SCAN_B 1024

typedef unsigned int uint;
typedef unsigned short ushort;

// ---- bf16 helpers (bit-level, RNE pack / exact unpack) ----
__device__ __forceinline__ float bf16_lo(uint u) {
    union { uint u; float f; } c; c.u = u << 16; return c.f;
}
__device__ __forceinline__ float bf16_hi(uint u) {
    union { uint u; float f; } c; c.u = u & 0xffff0000u; return c.f;
}
__device__ __forceinline__ uint f2b(float f) {   // returns bf16 in low 16 bits (RNE)
    union { float f; uint u; } c; c.f = f;
    return (c.u + 0x7fffu + ((c.u >> 16) & 1u)) >> 16;
}

// ---- f32 -> bf16 row conversion, 8 elems/thread ----
__global__ void cvt_bf16(const float* __restrict__ in, ushort* __restrict__ out, int n8) {
    int k = blockIdx.x * blockDim.x + threadIdx.x;
    if (k >= n8) return;
    const float4* p = (const float4*)in + (size_t)k * 2;
    float4 a = p[0], b = p[1];
    uint4 o;
    o.x = f2b(a.x) | (f2b(a.y) << 16);
    o.y = f2b(a.z) | (f2b(a.w) << 16);
    o.z = f2b(b.x) | (f2b(b.y) << 16);
    o.w = f2b(b.z) | (f2b(b.w) << 16);
    ((uint4*)out)[k] = o;
}

// ---- CSR build ----
__global__ void edge_hist(const int* __restrict__ src, const int* __restrict__ dst,
                          int* __restrict__ cnt_u, int* __restrict__ cnt_i, int E) {
    int e = blockIdx.x * blockDim.x + threadIdx.x;
    if (e >= E) return;
    int s = __builtin_nontemporal_load(&src[e]);
    int t = __builtin_nontemporal_load(&dst[e]);
    atomicAdd(&cnt_u[s], 1);
    atomicAdd(&cnt_i[t], 1);
}

// In-place per-chunk exclusive scan (reads a[i], writes a[i]; 1:1 thread:index).
__global__ void scan1(int* __restrict__ a, int* __restrict__ bsum, int n) {
    __shared__ int ws[16];
    int i = blockIdx.x * SCAN_B + threadIdx.x;
    int lane = threadIdx.x & 63, wid = threadIdx.x >> 6;
    int v = (i < n) ? a[i] : 0;
    int incl = v;
    #pragma unroll
    for (int off = 1; off < 64; off <<= 1) {
        int t = __shfl_up(incl, off, 64);
        if (lane >= off) incl += t;
    }
    if (lane == 63) ws[wid] = incl;
    __syncthreads();
    int woff = 0;
    for (int w = 0; w < wid; ++w) woff += ws[w];
    if (i < n) a[i] = woff + incl - v;
    if (threadIdx.x == SCAN_B - 1) bsum[blockIdx.x] = woff + incl;
}

__global__ void scan2(int* __restrict__ bsum, int nb) {
    __shared__ int ws[16];
    int lane = threadIdx.x & 63, wid = threadIdx.x >> 6;
    int v = ((int)threadIdx.x < nb) ? bsum[threadIdx.x] : 0;
    int incl = v;
    #pragma unroll
    for (int off = 1; off < 64; off <<= 1) {
        int t = __shfl_up(incl, off, 64);
        if (lane >= off) incl += t;
    }
    if (lane == 63) ws[wid] = incl;
    __syncthreads();
    int woff = 0;
    for (int w = 0; w < wid; ++w) woff += ws[w];
    if ((int)threadIdx.x < nb) bsum[threadIdx.x] = woff + incl - v;
}

__global__ void scan3(int* __restrict__ cur, const int* __restrict__ bsum, int n) {
    int i = blockIdx.x * SCAN_B + threadIdx.x;
    if (i < n) cur[i] += bsum[blockIdx.x];
}

// Range-partitioned single-pass CSR fill; cur_* become inclusive segment ends.
__global__ __launch_bounds__(256) void edge_fill_part(
        const int* __restrict__ src, const int* __restrict__ dst,
        int* __restrict__ cur_u, int* __restrict__ cur_i,
        int* __restrict__ col_u, int* __restrict__ col_i,
        int E, int n_users, int n_items) {
    int g    = blockIdx.x & (NG - 1);
    int bi   = blockIdx.x >> 3;
    int bpg  = gridDim.x >> 3;
    int nthr = bpg * blockDim.x;
    int tid  = bi * blockDim.x + threadIdx.x;

    int uchunk = (n_users + NG - 1) / NG;
    int ulo = g * uchunk, uhi = min(n_users, ulo + uchunk);
    int ichunk = (n_items + NG - 1) / NG;
    int ilo = g * ichunk, ihi = min(n_items, ilo + ichunk);

    for (int e = tid; e < E; e += nthr) {
        int s = __builtin_nontemporal_load(&src[e]);
        int t = __builtin_nontemporal_load(&dst[e]);
        if (s >= ulo && s < uhi) col_u[atomicAdd(&cur_u[s], 1)] = t;
        if (t >= ilo && t < ihi) col_i[atomicAdd(&cur_i[t], 1)] = s;
    }
}

// ---- bf16 gather-mean: one wave per node; lane=(r,c): r=row slot, c=16B chunk.
// COMBINE=0: outb[node] = bf16(mean);  COMBINE=1: outf = (x0 + x1 + mean)/3.
template <int COMBINE>
__global__ __launch_bounds__(256) void gather_b(
        const ushort* __restrict__ feat,
        const int* __restrict__ ends,
        const int* __restrict__ col,
        const float* __restrict__ x0,
        const ushort* __restrict__ x1,
        float* __restrict__ outf,
        ushort* __restrict__ outb,
        int n) {
    int node = blockIdx.x * 4 + (threadIdx.x >> 6);
    if (node >= n) return;
    int lane = threadIdx.x & 63;
    int r = lane >> 3, c = lane & 7;
    int beg = (node == 0) ? 0 : ends[node - 1];
    int end = ends[node];
    const ushort* fbase = feat + c * 8;

    float acc[8];
    #pragma unroll
    for (int j = 0; j < 8; ++j) acc[j] = 0.0f;

    for (int e = beg; e < end; e += 16) {
        int i0 = e + r, i1 = e + 8 + r;
        bool ok0 = i0 < end, ok1 = i1 < end;
        int nb0 = col[ok0 ? i0 : beg];
        int nb1 = col[ok1 ? i1 : beg];
        uint4 v0 = *(const uint4*)(fbase + (size_t)nb0 * DIM);
        uint4 v1 = *(const uint4*)(fbase + (size_t)nb1 * DIM);
        if (ok0) {
            acc[0] += bf16_lo(v0.x); acc[1] += bf16_hi(v0.x);
            acc[2] += bf16_lo(v0.y); acc[3] += bf16_hi(v0.y);
            acc[4] += bf16_lo(v0.z); acc[5] += bf16_hi(v0.z);
            acc[6] += bf16_lo(v0.w); acc[7] += bf16_hi(v0.w);
        }
        if (ok1) {
            acc[0] += bf16_lo(v1.x); acc[1] += bf16_hi(v1.x);
            acc[2] += bf16_lo(v1.y); acc[3] += bf16_hi(v1.y);
            acc[4] += bf16_lo(v1.z); acc[5] += bf16_hi(v1.z);
            acc[6] += bf16_lo(v1.w); acc[7] += bf16_hi(v1.w);
        }
    }
    #pragma unroll
    for (int m = 8; m < 64; m <<= 1) {
        #pragma unroll
        for (int j = 0; j < 8; ++j) acc[j] += __shfl_xor(acc[j], m, 64);
    }
    if (r == 0) {
        int d = end - beg;
        float inv = (d > 0) ? 1.0f / (float)d : 0.0f;
        size_t base = (size_t)node * DIM + c * 8;
        if (COMBINE) {
            float4 xa = *(const float4*)(x0 + base);
            float4 xb = *(const float4*)(x0 + base + 4);
            uint4  xq = *(const uint4*)(x1 + base);
            float4 oa, ob;
            oa.x = (xa.x + bf16_lo(xq.x) + acc[0] * inv) * (1.0f / 3.0f);
            oa.y = (xa.y + bf16_hi(xq.x) + acc[1] * inv) * (1.0f / 3.0f);
            oa.z = (xa.z + bf16_lo(xq.y) + acc[2] * inv) * (1.0f / 3.0f);
            oa.w = (xa.w + bf16_hi(xq.y) + acc[3] * inv) * (1.0f / 3.0f);
            ob.x = (xb.x + bf16_lo(xq.z) + acc[4] * inv) * (1.0f / 3.0f);
            ob.y = (xb.y + bf16_hi(xq.z) + acc[5] * inv) * (1.0f / 3.0f);
            ob.z = (xb.z + bf16_lo(xq.w) + acc[6] * inv) * (1.0f / 3.0f);
            ob.w = (xb.w + bf16_hi(xq.w) + acc[7] * inv) * (1.0f / 3.0f);
            *(float4*)(outf + base)     = oa;
            *(float4*)(outf + base + 4) = ob;
        } else {
            uint4 o;
            o.x = f2b(acc[0] * inv) | (f2b(acc[1] * inv) << 16);
            o.y = f2b(acc[2] * inv) | (f2b(acc[3] * inv) << 16);
            o.z = f2b(acc[4] * inv) | (f2b(acc[5] * inv) << 16);
            o.w = f2b(acc[6] * inv) | (f2b(acc[7] * inv) << 16);
            *(uint4*)(outb + base) = o;
        }
    }
}

extern "C" void kernel_launch(void* const* d_in, const int* in_sizes, int n_in,
                              void* d_out, int out_size, void* d_ws, size_t ws_size,
                              hipStream_t stream) {
    const float* u0  = (const float*)d_in[0];
    const float* i0  = (const float*)d_in[1];
    const int*   src = (const int*)d_in[2];
    const int*   dst = (const int*)d_in[3];

    const int n_users = in_sizes[0] / DIM;   // 200000
    const int n_items = in_sizes[1] / DIM;   // 100000
    const int E       = in_sizes[2];         // 3000000

    const size_t u_elems = (size_t)n_users * DIM;
    const size_t i_elems = (size_t)n_items * DIM;

    // Workspace layout (~76.4 MB):
    // cur_u | cur_i | col_u[E] | col_i[E] | bsum[1024] | ub[u_elems bf16] |
    // ib0[i_elems bf16] | ib1[i_elems bf16]
    int* cur_u = (int*)d_ws;
    int* cur_i = cur_u + n_users;
    int* col_u = cur_i + n_items;
    int* col_i = col_u + E;
    int* bsum  = col_i + E;
    ushort* ub  = (ushort*)(bsum + 1024);  // holds ub0, later overwritten by ub1
    ushort* ib0 = ub + u_elems;
    ushort* ib1 = ib0 + i_elems;

    float* out_u = (float*)d_out;
    float* out_i = out_u + u_elems;

    const int BLK = 256;
    const int eg = (E + BLK - 1) / BLK;
    const int nb_u = (n_users + SCAN_B - 1) / SCAN_B;
    const int nb_i = (n_items + SCAN_B - 1) / SCAN_B;

    // ---- bf16 staging of inputs (overlaps CSR build on the same stream) ----
    cvt_bf16<<<(int)((u_elems / 8 + BLK - 1) / BLK), BLK, 0, stream>>>(u0, ub, (int)(u_elems / 8));
    cvt_bf16<<<(int)((i_elems / 8 + BLK - 1) / BLK), BLK, 0, stream>>>(i0, ib0, (int)(i_elems / 8));

    // ---- CSR build ----
    hipMemsetAsync(cur_u, 0, (size_t)(n_users + n_items) * sizeof(int), stream);
    edge_hist<<<eg, BLK, 0, stream>>>(src, dst, cur_u, cur_i, E);
    scan1<<<nb_u, SCAN_B, 0, stream>>>(cur_u, bsum, n_users);
    scan2<<<1, SCAN_B, 0, stream>>>(bsum, nb_u);
    scan3<<<nb_u, SCAN_B, 0, stream>>>(cur_u, bsum, n_users);
    scan1<<<nb_i, SCAN_B, 0, stream>>>(cur_i, bsum, n_items);
    scan2<<<1, SCAN_B, 0, stream>>>(bsum, nb_i);
    scan3<<<nb_i, SCAN_B, 0, stream>>>(cur_i, bsum, n_items);
    edge_fill_part<<<NG * 160, BLK, 0, stream>>>(src, dst, cur_u, cur_i,
                                                 col_u, col_i, E, n_users, n_items);
    // cur_u / cur_i now hold inclusive segment ends.

    const int ug = (n_users + 3) / 4;
    const int ig = (n_items + 3) / 4;

    // ---- Layer 1 (order matters for the ub slot reuse) ----
    // i1 = mean(u0-nbrs): reads ub0 -> ib1
    gather_b<0><<<ig, BLK, 0, stream>>>(ub, cur_i, col_i, nullptr, nullptr,
                                        nullptr, ib1, n_items);
    // u1 = mean(i0-nbrs): reads ib0 -> ub (ub0 dead after previous launch)
    gather_b<0><<<ug, BLK, 0, stream>>>(ib0, cur_u, col_u, nullptr, nullptr,
                                        nullptr, ub, n_users);

    // ---- Layer 2, fused with final combine ----
    // out_i = (i0 + i1 + mean(u1-nbrs)) / 3
    gather_b<1><<<ig, BLK, 0, stream>>>(ub, cur_i, col_i, i0, ib1,
                                        out_i, nullptr, n_items);
    // out_u = (u0 + u1 + mean(i1-nbrs)) / 3
    gather_b<1><<<ug, BLK, 0, stream>>>(ib1, cur_u, col_u, u0, ub,
                                        out_u, nullptr, n_users);
}

// Round 5
// 936.369 us; speedup vs baseline: 3.1246x; 1.0180x over previous
//
#include <hip/hip_runtime.h>

#define DIM 64
#define NG 8
#define SCAN_B 1024

typedef unsigned int uint;
typedef unsigned short ushort;

// ---- bf16 helpers ----
__device__ __forceinline__ float bf16_lo(uint u) {
    union { uint u; float f; } c; c.u = u << 16; return c.f;
}
__device__ __forceinline__ float bf16_hi(uint u) {
    union { uint u; float f; } c; c.u = u & 0xffff0000u; return c.f;
}
__device__ __forceinline__ uint f2b(float f) {   // bf16 in low 16 bits (RNE)
    union { float f; uint u; } c; c.f = f;
    return (c.u + 0x7fffu + ((c.u >> 16) & 1u)) >> 16;
}

// f32 -> bf16, 8 elems/thread, output row pitch/offset in ushorts (rows of 64).
__global__ void cvt_bf16_pitch(const float* __restrict__ in, ushort* __restrict__ out,
                               int n8, int pitch, int off) {
    int k = blockIdx.x * blockDim.x + threadIdx.x;
    if (k >= n8) return;
    int row = k >> 3, g = k & 7;
    const float4* p = (const float4*)in + (size_t)k * 2;
    float4 a = p[0], b = p[1];
    uint4 o;
    o.x = f2b(a.x) | (f2b(a.y) << 16);
    o.y = f2b(a.z) | (f2b(a.w) << 16);
    o.z = f2b(b.x) | (f2b(b.y) << 16);
    o.w = f2b(b.z) | (f2b(b.w) << 16);
    *(uint4*)(out + (size_t)row * pitch + off + g * 8) = o;
}

// ---- CSR build (combined: deg[0..n_users) users, deg[n_users..) items) ----
__global__ void edge_hist(const int* __restrict__ src, const int* __restrict__ dst,
                          int* __restrict__ deg, int n_users, int E) {
    int e = blockIdx.x * blockDim.x + threadIdx.x;
    if (e >= E) return;
    int s = __builtin_nontemporal_load(&src[e]);
    int t = __builtin_nontemporal_load(&dst[e]);
    atomicAdd(&deg[s], 1);
    atomicAdd(&deg[n_users + t], 1);
}

__global__ void scan1(int* __restrict__ a, int* __restrict__ bsum, int n) {
    __shared__ int ws[16];
    int i = blockIdx.x * SCAN_B + threadIdx.x;
    int lane = threadIdx.x & 63, wid = threadIdx.x >> 6;
    int v = (i < n) ? a[i] : 0;
    int incl = v;
    #pragma unroll
    for (int off = 1; off < 64; off <<= 1) {
        int t = __shfl_up(incl, off, 64);
        if (lane >= off) incl += t;
    }
    if (lane == 63) ws[wid] = incl;
    __syncthreads();
    int woff = 0;
    for (int w = 0; w < wid; ++w) woff += ws[w];
    if (i < n) a[i] = woff + incl - v;
    if (threadIdx.x == SCAN_B - 1) bsum[blockIdx.x] = woff + incl;
}

__global__ void scan2(int* __restrict__ bsum, int nb) {
    __shared__ int ws[16];
    int lane = threadIdx.x & 63, wid = threadIdx.x >> 6;
    int v = ((int)threadIdx.x < nb) ? bsum[threadIdx.x] : 0;
    int incl = v;
    #pragma unroll
    for (int off = 1; off < 64; off <<= 1) {
        int t = __shfl_up(incl, off, 64);
        if (lane >= off) incl += t;
    }
    if (lane == 63) ws[wid] = incl;
    __syncthreads();
    int woff = 0;
    for (int w = 0; w < wid; ++w) woff += ws[w];
    if ((int)threadIdx.x < nb) bsum[threadIdx.x] = woff + incl - v;
}

__global__ void scan3(int* __restrict__ cur, const int* __restrict__ bsum, int n) {
    int i = blockIdx.x * SCAN_B + threadIdx.x;
    if (i < n) cur[i] += bsum[blockIdx.x];
}

// Range-partitioned two-pass fill (per-direction loops keep the dirty write
// working set per group at one 1.5 MB slice). deg -> inclusive segment ends.
__global__ __launch_bounds__(256) void edge_fill_part(
        const int* __restrict__ src, const int* __restrict__ dst,
        int* __restrict__ deg, int* __restrict__ col,
        int E, int n_users, int n_items) {
    int g    = blockIdx.x & (NG - 1);
    int bi   = blockIdx.x >> 3;
    int bpg  = gridDim.x >> 3;
    int nthr = bpg * blockDim.x;
    int tid  = bi * blockDim.x + threadIdx.x;

    int uchunk = (n_users + NG - 1) / NG;
    int ulo = g * uchunk, uhi = min(n_users, ulo + uchunk);
    int ichunk = (n_items + NG - 1) / NG;
    int ilo = g * ichunk, ihi = min(n_items, ilo + ichunk);

    for (int e = tid; e < E; e += nthr) {
        int s = __builtin_nontemporal_load(&src[e]);
        if (s >= ulo && s < uhi) {
            int t = __builtin_nontemporal_load(&dst[e]);
            col[atomicAdd(&deg[s], 1)] = t;
        }
    }
    for (int e = tid; e < E; e += nthr) {
        int t = __builtin_nontemporal_load(&dst[e]);
        if (t >= ilo && t < ihi) {
            int s = __builtin_nontemporal_load(&src[e]);
            col[atomicAdd(&deg[n_users + t], 1)] = s;
        }
    }
}

// ---- 128B-row gather (one wave per node; r=lane>>3 row slot, c=lane&7 chunk).
// ends[-1] must be valid (sentinel). COMBINE=0: bf16 out at (ob_pitch, ob_off).
// COMBINE=1: outf = (x0 + x1 + mean)/3, x1 bf16 at (x1_pitch, x1_off).
// NOTE: outf may alias x1's buffer (same row, same wave) — data dependency
// (store value uses loaded x1) keeps this safe; no __restrict__ on those.
template <int COMBINE>
__global__ __launch_bounds__(256) void gather128(
        const ushort* __restrict__ feat,
        const int* __restrict__ ends,
        const int* __restrict__ col,
        const float* __restrict__ x0,
        const ushort* x1, int x1_pitch, int x1_off,
        float* outf,
        ushort* outb, int ob_pitch, int ob_off,
        int n) {
    int node = blockIdx.x * 4 + (threadIdx.x >> 6);
    if (node >= n) return;
    int lane = threadIdx.x & 63;
    int r = lane >> 3, c = lane & 7;
    int beg = ends[node - 1];
    int end = ends[node];
    const ushort* fbase = feat + c * 8;

    float acc[8];
    #pragma unroll
    for (int j = 0; j < 8; ++j) acc[j] = 0.0f;

    for (int e = beg; e < end; e += 16) {
        int i0 = e + r, i1 = e + 8 + r;
        bool ok0 = i0 < end, ok1 = i1 < end;
        int nb0 = col[ok0 ? i0 : beg];
        int nb1 = col[ok1 ? i1 : beg];
        uint4 v0 = *(const uint4*)(fbase + (size_t)nb0 * DIM);
        uint4 v1 = *(const uint4*)(fbase + (size_t)nb1 * DIM);
        if (ok0) {
            acc[0] += bf16_lo(v0.x); acc[1] += bf16_hi(v0.x);
            acc[2] += bf16_lo(v0.y); acc[3] += bf16_hi(v0.y);
            acc[4] += bf16_lo(v0.z); acc[5] += bf16_hi(v0.z);
            acc[6] += bf16_lo(v0.w); acc[7] += bf16_hi(v0.w);
        }
        if (ok1) {
            acc[0] += bf16_lo(v1.x); acc[1] += bf16_hi(v1.x);
            acc[2] += bf16_lo(v1.y); acc[3] += bf16_hi(v1.y);
            acc[4] += bf16_lo(v1.z); acc[5] += bf16_hi(v1.z);
            acc[6] += bf16_lo(v1.w); acc[7] += bf16_hi(v1.w);
        }
    }
    #pragma unroll
    for (int m = 8; m < 64; m <<= 1) {
        #pragma unroll
        for (int j = 0; j < 8; ++j) acc[j] += __shfl_xor(acc[j], m, 64);
    }
    if (r == 0) {
        int d = end - beg;
        float inv = (d > 0) ? 1.0f / (float)d : 0.0f;
        if (COMBINE) {
            size_t base = (size_t)node * DIM + c * 8;
            float4 xa = *(const float4*)(x0 + base);
            float4 xb = *(const float4*)(x0 + base + 4);
            uint4  xq = *(const uint4*)(x1 + (size_t)node * x1_pitch + x1_off + c * 8);
            float4 oa, ob;
            oa.x = (xa.x + bf16_lo(xq.x) + acc[0] * inv) * (1.0f / 3.0f);
            oa.y = (xa.y + bf16_hi(xq.x) + acc[1] * inv) * (1.0f / 3.0f);
            oa.z = (xa.z + bf16_lo(xq.y) + acc[2] * inv) * (1.0f / 3.0f);
            oa.w = (xa.w + bf16_hi(xq.y) + acc[3] * inv) * (1.0f / 3.0f);
            ob.x = (xb.x + bf16_lo(xq.z) + acc[4] * inv) * (1.0f / 3.0f);
            ob.y = (xb.y + bf16_hi(xq.z) + acc[5] * inv) * (1.0f / 3.0f);
            ob.z = (xb.z + bf16_lo(xq.w) + acc[6] * inv) * (1.0f / 3.0f);
            ob.w = (xb.w + bf16_hi(xq.w) + acc[7] * inv) * (1.0f / 3.0f);
            *(float4*)(outf + base)     = oa;
            *(float4*)(outf + base + 4) = ob;
        } else {
            uint4 o;
            o.x = f2b(acc[0] * inv) | (f2b(acc[1] * inv) << 16);
            o.y = f2b(acc[2] * inv) | (f2b(acc[3] * inv) << 16);
            o.z = f2b(acc[4] * inv) | (f2b(acc[5] * inv) << 16);
            o.w = f2b(acc[6] * inv) | (f2b(acc[7] * inv) << 16);
            *(uint4*)(outb + (size_t)node * ob_pitch + ob_off + c * 8) = o;
        }
    }
}

// ---- 256B-row fused item pass: feat = u01 (u0|u1 interleaved, pitch 128).
// Computes i1 = mean(u0-nbrs), i2 = mean(u1-nbrs) in ONE col walk.
// outf = (x0 + i1 + i2)/3 (f32), outb = bf16(i1) (dense pitch 64).
__global__ __launch_bounds__(256) void gather256_combine(
        const ushort* __restrict__ feat,
        const int* __restrict__ ends,
        const int* __restrict__ col,
        const float* __restrict__ x0,
        float* __restrict__ outf,
        ushort* __restrict__ outb,
        int n) {
    int node = blockIdx.x * 4 + (threadIdx.x >> 6);
    if (node >= n) return;
    int lane = threadIdx.x & 63;
    int c = lane & 15, r = lane >> 4;          // c: 16B chunk of 256B row
    int beg = ends[node - 1];
    int end = ends[node];
    const ushort* fbase = feat + c * 8;

    float acc[8];
    #pragma unroll
    for (int j = 0; j < 8; ++j) acc[j] = 0.0f;

    for (int e = beg; e < end; e += 8) {
        int i0 = e + r, i1 = e + 4 + r;
        bool ok0 = i0 < end, ok1 = i1 < end;
        int nb0 = col[ok0 ? i0 : beg];
        int nb1 = col[ok1 ? i1 : beg];
        uint4 v0 = *(const uint4*)(fbase + (size_t)nb0 * 128);
        uint4 v1 = *(const uint4*)(fbase + (size_t)nb1 * 128);
        if (ok0) {
            acc[0] += bf16_lo(v0.x); acc[1] += bf16_hi(v0.x);
            acc[2] += bf16_lo(v0.y); acc[3] += bf16_hi(v0.y);
            acc[4] += bf16_lo(v0.z); acc[5] += bf16_hi(v0.z);
            acc[6] += bf16_lo(v0.w); acc[7] += bf16_hi(v0.w);
        }
        if (ok1) {
            acc[0] += bf16_lo(v1.x); acc[1] += bf16_hi(v1.x);
            acc[2] += bf16_lo(v1.y); acc[3] += bf16_hi(v1.y);
            acc[4] += bf16_lo(v1.z); acc[5] += bf16_hi(v1.z);
            acc[6] += bf16_lo(v1.w); acc[7] += bf16_hi(v1.w);
        }
    }
    // fold the 4 r-slots (lane bits 4,5)
    #pragma unroll
    for (int m = 16; m < 64; m <<= 1) {
        #pragma unroll
        for (int j = 0; j < 8; ++j) acc[j] += __shfl_xor(acc[j], m, 64);
    }
    // partner exchange: lane c (<8, u0-part) pairs with lane c+8 (u1-part, same elems)
    float b8[8];
    #pragma unroll
    for (int j = 0; j < 8; ++j) b8[j] = __shfl_xor(acc[j], 8, 64);

    if (r == 0 && c < 8) {
        int d = end - beg;
        float inv = (d > 0) ? 1.0f / (float)d : 0.0f;
        size_t base = (size_t)node * DIM + c * 8;
        float4 xa = *(const float4*)(x0 + base);
        float4 xb = *(const float4*)(x0 + base + 4);
        float i1v[8];
        #pragma unroll
        for (int j = 0; j < 8; ++j) i1v[j] = acc[j] * inv;
        float4 oa, ob;
        oa.x = (xa.x + i1v[0] + b8[0] * inv) * (1.0f / 3.0f);
        oa.y = (xa.y + i1v[1] + b8[1] * inv) * (1.0f / 3.0f);
        oa.z = (xa.z + i1v[2] + b8[2] * inv) * (1.0f / 3.0f);
        oa.w = (xa.w + i1v[3] + b8[3] * inv) * (1.0f / 3.0f);
        ob.x = (xb.x + i1v[4] + b8[4] * inv) * (1.0f / 3.0f);
        ob.y = (xb.y + i1v[5] + b8[5] * inv) * (1.0f / 3.0f);
        ob.z = (xb.z + i1v[6] + b8[6] * inv) * (1.0f / 3.0f);
        ob.w = (xb.w + i1v[7] + b8[7] * inv) * (1.0f / 3.0f);
        *(float4*)(outf + base)     = oa;
        *(float4*)(outf + base + 4) = ob;
        uint4 q;
        q.x = f2b(i1v[0]) | (f2b(i1v[1]) << 16);
        q.y = f2b(i1v[2]) | (f2b(i1v[3]) << 16);
        q.z = f2b(i1v[4]) | (f2b(i1v[5]) << 16);
        q.w = f2b(i1v[6]) | (f2b(i1v[7]) << 16);
        *(uint4*)(outb + base) = q;
    }
}

extern "C" void kernel_launch(void* const* d_in, const int* in_sizes, int n_in,
                              void* d_out, int out_size, void* d_ws, size_t ws_size,
                              hipStream_t stream) {
    const float* u0  = (const float*)d_in[0];
    const float* i0  = (const float*)d_in[1];
    const int*   src = (const int*)d_in[2];
    const int*   dst = (const int*)d_in[3];

    const int n_users = in_sizes[0] / DIM;   // 200000
    const int n_items = in_sizes[1] / DIM;   // 100000
    const int E       = in_sizes[2];         // 3000000
    const int n_nodes = n_users + n_items;

    const size_t u_elems = (size_t)n_users * DIM;
    const size_t i_elems = (size_t)n_items * DIM;

    // Workspace (~38 MB): cur_full[n_nodes+1] | col[2E] | bsum[1024] | ib[i_elems bf16]
    int* cur_full = (int*)d_ws;       // [0] = 0 sentinel, deg = cur_full+1
    int* deg  = cur_full + 1;
    int* col  = cur_full + (n_nodes + 1);
    int* bsum = col + 2 * (size_t)E;
    ushort* ib = (ushort*)(bsum + 1024);   // holds i0 bf16, later overwritten by i1 bf16

    // d_out: user region doubles as u01 (u0|u1 interleaved bf16, 256B rows).
    float* out_u = (float*)d_out;
    float* out_i = out_u + u_elems;
    ushort* u01  = (ushort*)d_out;         // exactly overlays out_u (51.2 MB)

    const int BLK = 256;
    const int nb = (n_nodes + SCAN_B - 1) / SCAN_B;

    // ---- stage bf16: u0 -> u01 even halves; i0 -> ib (dense) ----
    cvt_bf16_pitch<<<(int)((u_elems / 8 + BLK - 1) / BLK), BLK, 0, stream>>>(
        u0, u01, (int)(u_elems / 8), 128, 0);
    cvt_bf16_pitch<<<(int)((i_elems / 8 + BLK - 1) / BLK), BLK, 0, stream>>>(
        i0, ib, (int)(i_elems / 8), 64, 0);

    // ---- CSR build (combined users+items, single scan, sentinel at [-1]) ----
    hipMemsetAsync(cur_full, 0, (size_t)(n_nodes + 1) * sizeof(int), stream);
    edge_hist<<<(E + BLK - 1) / BLK, BLK, 0, stream>>>(src, dst, deg, n_users, E);
    scan1<<<nb, SCAN_B, 0, stream>>>(deg, bsum, n_nodes);
    scan2<<<1, SCAN_B, 0, stream>>>(bsum, nb);
    scan3<<<nb, SCAN_B, 0, stream>>>(deg, bsum, n_nodes);
    edge_fill_part<<<NG * 256, BLK, 0, stream>>>(src, dst, deg, col, E, n_users, n_items);
    // deg now holds inclusive segment ends (users: [0..), items at deg+n_users).

    const int ug = (n_users + 3) / 4;
    const int ig = (n_items + 3) / 4;

    // ---- Pass A: u1 = mean(i0-nbrs) -> u01 odd halves (bf16) ----
    gather128<0><<<ug, BLK, 0, stream>>>(ib, deg, col, nullptr,
                                         nullptr, 0, 0, nullptr,
                                         u01, 128, 64, n_users);

    // ---- Pass C: fused item pass: out_i = (i0 + i1 + i2)/3, ib <- bf16(i1) ----
    gather256_combine<<<ig, BLK, 0, stream>>>(u01, deg + n_users, col,
                                              i0, out_i, ib, n_items);

    // ---- Pass D: out_u = (u0 + u1 + mean(i1-nbrs))/3 (u1 from u01 odd) ----
    gather128<1><<<ug, BLK, 0, stream>>>(ib, deg, col, u0,
                                         u01, 128, 64, out_u,
                                         nullptr, 0, 0, n_users);
}